// Round 6
// baseline (57.126 us; speedup 1.0000x reference)
//
#include <hip/hip_runtime.h>
#include <hip/hip_fp16.h>

// 11-layer MLP (8->6x6->4x4->1), sigmoid each layer, B=4.19M rows.
// R6 = R5 (packed-f16, poly sigmoid, prep-converted broadcast weights) with
// 4 rows/thread as TWO independent half2 pipelines (groups A,B) sharing each
// weight scalar-load: two v_pk_fma_f16 per weight. Doubles in-thread ILP and
// halves per-row scalar-load wait overhead (R5 was latency-bound at ~6.5
// cyc/instr vs the 2 cyc issue floor). All array indices compile-time
// constant (SROA-safe); live state 16 VGPRs of activations.

typedef _Float16 f16x2 __attribute__((ext_vector_type(2)));

struct WPtrs { const float* W[11]; const float* b[11]; };

// ws layout (u32 units): W1@0(48) b1@48(6) W2@54 b2@90 W3@96 b3@132 W4@138
// b4@174 W5@180 b5@216 W6@222 b6@258 W7@264(24) b7@288(4) W8@292 b8@308
// W9@312 b9@328 W10@332 b10@348 W11@352(4) b11@356(1)  -> 357 total
__global__ void prep_weights(WPtrs p, unsigned int* ws) {
    int t = (int)threadIdx.x;
    const int wsz[11] = {48, 36, 36, 36, 36, 36, 24, 16, 16, 16, 4};
    const int bsz[11] = {6, 6, 6, 6, 6, 6, 4, 4, 4, 4, 1};
    int off = 0;
    for (int l = 0; l < 11; ++l) {
        if (t >= off && t < off + wsz[l]) {
            unsigned short hb = __half_as_ushort(__float2half_rn(p.W[l][t - off]));
            ws[t] = (unsigned int)hb * 0x00010001u;
        }
        off += wsz[l];
        if (t >= off && t < off + bsz[l]) {
            unsigned short hb = __half_as_ushort(__float2half_rn(p.b[l][t - off]));
            ws[t] = (unsigned int)hb * 0x00010001u;
        }
        off += bsz[l];
    }
}

__device__ __forceinline__ __half2 clamp33(__half2 x) {
    f16x2 v;
    __builtin_memcpy(&v, &x, 4);
    f16x2 lo = {(_Float16)-3.0f, (_Float16)-3.0f};
    f16x2 hi = {(_Float16)3.0f, (_Float16)3.0f};
    v = __builtin_elementwise_min(__builtin_elementwise_max(v, lo), hi);
    __half2 r;
    __builtin_memcpy(&r, &v, 4);
    return r;
}

// sigma(z) ~= 0.5 + z*(b0 + b1 v + b2 v^2 + b3 v^3 + b4 v^4), v = z^2/8.
// Newton-interpolated on |z|<=3, |err| <~ 1e-4. No division, no exp.
__device__ __forceinline__ __half2 sigp(__half2 z) {
    __half2 u = __hmul2(z, z);
    __half2 v = __hmul2(u, __float2half2_rn(0.125f));
    __half2 p = __hfma2(v, __float2half2_rn(0.0136000f), __float2half2_rn(-0.0578102f));
    p = __hfma2(v, p, __float2half2_rn(0.1153824f));
    p = __hfma2(v, p, __float2half2_rn(-0.1640721f));
    p = __hfma2(v, p, __float2half2_rn(0.2499353f));
    return __hfma2(z, p, __float2half2_rn(0.5f));
}

template <int FI, int FO, int WOFF, int BOFF, bool CLAMP>
__device__ __forceinline__ void layerh4(const __half2* __restrict__ ws,
                                        const __half2 (&hA)[8], const __half2 (&hB)[8],
                                        __half2 (&oA)[8], __half2 (&oB)[8]) {
#pragma unroll
    for (int j = 0; j < FO; ++j) {
        __half2 accA = ws[BOFF + j];
        __half2 accB = accA;
#pragma unroll
        for (int i = 0; i < FI; ++i) {
            __half2 w = ws[WOFF + j * FI + i];
            accA = __hfma2(hA[i], w, accA);
            accB = __hfma2(hB[i], w, accB);
        }
        if (CLAMP) { accA = clamp33(accA); accB = clamp33(accB); }
        oA[j] = sigp(accA);
        oB[j] = sigp(accB);
    }
}

__global__ __launch_bounds__(256) void mlp11_f16x4(
    const float* __restrict__ x, const __half2* __restrict__ ws,
    float* __restrict__ out, int nquads, int nrows) {
    int t = blockIdx.x * 256 + (int)threadIdx.x;
    if (t >= nquads) return;

    int base = t * 4;
    bool full = (base + 3) < nrows;
    int r0 = base;
    int r1 = min(base + 1, nrows - 1);
    int r2 = min(base + 2, nrows - 1);
    int r3 = min(base + 3, nrows - 1);

    const float4* xv = reinterpret_cast<const float4*>(x);
    float4 a0 = xv[(size_t)r0 * 2], a1 = xv[(size_t)r0 * 2 + 1];
    float4 b0 = xv[(size_t)r1 * 2], b1 = xv[(size_t)r1 * 2 + 1];
    float4 c0 = xv[(size_t)r2 * 2], c1 = xv[(size_t)r2 * 2 + 1];
    float4 d0 = xv[(size_t)r3 * 2], d1 = xv[(size_t)r3 * 2 + 1];

    __half2 hA[8], hB[8], gA[8], gB[8];
    hA[0] = __floats2half2_rn(a0.x, b0.x);
    hA[1] = __floats2half2_rn(a0.y, b0.y);
    hA[2] = __floats2half2_rn(a0.z, b0.z);
    hA[3] = __floats2half2_rn(a0.w, b0.w);
    hA[4] = __floats2half2_rn(a1.x, b1.x);
    hA[5] = __floats2half2_rn(a1.y, b1.y);
    hA[6] = __floats2half2_rn(a1.z, b1.z);
    hA[7] = __floats2half2_rn(a1.w, b1.w);
    hB[0] = __floats2half2_rn(c0.x, d0.x);
    hB[1] = __floats2half2_rn(c0.y, d0.y);
    hB[2] = __floats2half2_rn(c0.z, d0.z);
    hB[3] = __floats2half2_rn(c0.w, d0.w);
    hB[4] = __floats2half2_rn(c1.x, d1.x);
    hB[5] = __floats2half2_rn(c1.y, d1.y);
    hB[6] = __floats2half2_rn(c1.z, d1.z);
    hB[7] = __floats2half2_rn(c1.w, d1.w);

    layerh4<8, 6, 0,   48,  true >(ws, hA, hB, gA, gB);  // L1 (clamped)
    layerh4<6, 6, 54,  90,  false>(ws, gA, gB, hA, hB);  // L2
    layerh4<6, 6, 96,  132, false>(ws, hA, hB, gA, gB);  // L3
    layerh4<6, 6, 138, 174, false>(ws, gA, gB, hA, hB);  // L4
    layerh4<6, 6, 180, 216, false>(ws, hA, hB, gA, gB);  // L5
    layerh4<6, 6, 222, 258, false>(ws, gA, gB, hA, hB);  // L6
    layerh4<6, 4, 264, 288, false>(ws, hA, hB, gA, gB);  // L7
    layerh4<4, 4, 292, 308, false>(ws, gA, gB, hA, hB);  // L8
    layerh4<4, 4, 312, 328, false>(ws, hA, hB, gA, gB);  // L9
    layerh4<4, 4, 332, 348, false>(ws, gA, gB, hA, hB);  // L10

    // L11: 4 -> 1
    __half2 accA = ws[356];
    __half2 accB = accA;
#pragma unroll
    for (int i = 0; i < 4; ++i) {
        __half2 w = ws[352 + i];
        accA = __hfma2(hA[i], w, accA);
        accB = __hfma2(hB[i], w, accB);
    }
    __half2 sA = sigp(accA);
    __half2 sB = sigp(accB);

    if (full) {
        reinterpret_cast<float4*>(out)[t] =
            make_float4(__low2float(sA), __high2float(sA),
                        __low2float(sB), __high2float(sB));
    } else {
        float v[4] = {__low2float(sA), __high2float(sA),
                      __low2float(sB), __high2float(sB)};
        for (int k = 0; k < 4; ++k)
            if (base + k < nrows) out[base + k] = v[k];
    }
}

extern "C" void kernel_launch(void* const* d_in, const int* in_sizes, int n_in,
                              void* d_out, int out_size, void* d_ws, size_t ws_size,
                              hipStream_t stream) {
    const float* x = (const float*)d_in[0];
    WPtrs p;
    for (int i = 0; i < 11; ++i) {
        p.W[i] = (const float*)d_in[1 + 2 * i];
        p.b[i] = (const float*)d_in[2 + 2 * i];
    }
    float* out = (float*)d_out;
    int nrows = in_sizes[0] / 8;
    int nquads = (nrows + 3) / 4;

    prep_weights<<<1, 512, 0, stream>>>(p, (unsigned int*)d_ws);

    int blocks = (nquads + 255) / 256;
    mlp11_f16x4<<<blocks, 256, 0, stream>>>(
        x, (const __half2*)d_ws, out, nquads, nrows);
}